// Round 5
// baseline (278.506 us; speedup 1.0000x reference)
//
#include <hip/hip_runtime.h>

// R10: hybrid of R5's x-reuse and R9's layer-wise ILP.
// Evidence: R9 (~97us inferred) beat R6/R8 (128-130) but still trails the
// original R5 d-loop kernel (~87-90us, dur 251). R5 won on x-reuse (x regs
// shared by 16 fields, 240 MFMAs/wave); fixed-d lost that (FETCH 12->47MB,
// shallow per-wave work). R10: each block owns a 4-field group + 1600 pts;
// each wave = 400 pts x 4 fields:
//   - one x-frag per tile shared by 4 fields; packed once (2 pkrtz+2 cndmask)
//   - layer-wise across fields: 4 independent MFMAs back-to-back per layer
//     (acc[4] = 16 VGPRs live -> compiler cannot re-serialize to save regs)
//   - 300 MFMAs/wave; next-tile x prefetched via register rotate
//   - weights of 4 fields in registers (~72 VGPRs); no LDS, no syncthreads
//   - XCD swizzle: bid = r + 8*dg + 32*a, chunk = 8a+r -> a chunk's 4
//     dgroup-blocks run on XCD chunk%8 within a 32-block dispatch window.
// Numerics bitwise-identical to R8/R9 per (field,point): a1 quad-broadcast,
// B-frag quads>=1 zeroed via cndmask, relu = fmaxf(f32) then cvt_pkrtz,
// biases ride the MFMA C operand (fp32). Weights RNE-cast, activations RTZ.
//
// Frag layouts (16x16x16, CDNA family):
//   A[m][k]: lane m=lane&15, k = 4*(lane>>4) + j   (4 f16, 2 VGPRs)
//   B[k][n]: lane n=lane&15, k = 4*(lane>>4) + j
//   C/D:     lane n=lane&15, row = 4*(lane>>4) + i (4 fp32)

#define MFMA16(a, b, c) __builtin_amdgcn_mfma_f32_16x16x16f16((a), (b), (c), 0, 0, 0)

#define TILES_PER_WAVE 25
#define WAVES_PER_BLOCK 4
#define FPB 4                                            // fields per block
#define PTS_PER_WAVE (TILES_PER_WAVE * 16)               // 400
#define PTS_PER_BLOCK (PTS_PER_WAVE * WAVES_PER_BLOCK)   // 1600; 1e6 = 625*1600

typedef __fp16 pk16x2 __attribute__((ext_vector_type(2)));   // cvt_pkrtz return
typedef _Float16 half4_t __attribute__((ext_vector_type(4)));
typedef float float4_t __attribute__((ext_vector_type(4)));

union H2I { pk16x2 h; int i; };
union Frag { half4_t v; int i[2]; };

__device__ __forceinline__ int pkrtz(float a, float b) {
    H2I u; u.h = __builtin_amdgcn_cvt_pkrtz(a, b); return u.i;
}

__global__ __launch_bounds__(256) void fields_r10_kernel(
    const float* __restrict__ x,
    const float* __restrict__ W1, const float* __restrict__ b1,
    const float* __restrict__ W2, const float* __restrict__ b2,
    const float* __restrict__ W3, const float* __restrict__ b3,
    float* __restrict__ out, int N)
{
    const int lane = threadIdx.x & 63;
    const int wave = threadIdx.x >> 6;
    const int q    = lane >> 4;        // quad 0..3
    const int n16  = lane & 15;        // point within tile / row m for A

    // ---- XCD-swizzled decode: chunk c = 8a + r runs on XCD r = c%8;
    //      the 4 dgroup-blocks of a chunk sit in one 32-block window. ----
    const int bid = blockIdx.x;
    const int r   = bid & 7;
    const int dg  = (bid >> 3) & 3;    // field group: fields 4*dg .. 4*dg+3
    const int a   = bid >> 5;
    const int chunk  = a * 8 + r;
    const int chunks = (N + PTS_PER_BLOCK - 1) / PTS_PER_BLOCK;
    if (chunk >= chunks) return;       // pad blocks (grid rounded to *8)

    const int base = chunk * PTS_PER_BLOCK + wave * PTS_PER_WAVE;
    const bool isq0 = (q == 0);

    // ---- 4 fields' weights -> registers, frag-ready (constant-indexed) ----
    Frag a1w[FPB], a2w[FPB], a3w[FPB];
    float4_t b1v[FPB], b2v[FPB], b3v[FPB];
#pragma unroll
    for (int f = 0; f < FPB; ++f) {
        const int d = dg * FPB + f;
        const float* w1 = W1 + (d * 16 + n16) * 3;
        a1w[f].v = (half4_t){(_Float16)w1[0], (_Float16)w1[1],
                             (_Float16)w1[2], (_Float16)0.f};
        const float4_t w2 = *(const float4_t*)(W2 + (d * 16 + n16) * 16 + q * 4);
        a2w[f].v = (half4_t){(_Float16)w2.x, (_Float16)w2.y, (_Float16)w2.z,
                             (_Float16)w2.w};
        if (n16 < 3) {
            const float4_t w3 = *(const float4_t*)(W3 + (d * 3 + n16) * 16 + q * 4);
            a3w[f].v = (half4_t){(_Float16)w3.x, (_Float16)w3.y, (_Float16)w3.z,
                                 (_Float16)w3.w};
        } else {
            a3w[f].i[0] = 0; a3w[f].i[1] = 0;
        }
        b1v[f] = *(const float4_t*)(b1 + d * 16 + q * 4);
        b2v[f] = *(const float4_t*)(b2 + d * 16 + q * 4);
        float4_t bb3 = (float4_t){0.f, 0.f, 0.f, 0.f};
        if (isq0) {
            bb3.x = b3[d * 3 + 0];
            bb3.y = b3[d * 3 + 1];
            bb3.z = b3[d * 3 + 2];
        }
        b3v[f] = bb3;
    }

    // ---- base pointers (uniform bases -> SGPR; lane offset in VGPR) ----
    const float* xp0 = x + base + n16;
    const float* xp1 = xp0 + N;
    const float* xp2 = xp1 + N;
    float* op0[FPB]; float* op1[FPB]; float* op2[FPB];
#pragma unroll
    for (int f = 0; f < FPB; ++f) {
        const int d = dg * FPB + f;
        op0[f] = out + (size_t)(d * 3 + 0) * N + base + n16;
        op1[f] = out + (size_t)(d * 3 + 1) * N + base + n16;
        op2[f] = out + (size_t)(d * 3 + 2) * N + base + n16;
    }

    if (base + PTS_PER_WAVE <= N) {
        // ===== fast path: register-rotate prefetch + layer-wise 4-field ILP
        float c0 = xp0[0], c1 = xp1[0], c2 = xp2[0];
#pragma unroll
        for (int t = 0; t < TILES_PER_WAVE; ++t) {
            const int off = t * 16;
            float nx0 = 0.f, nx1 = 0.f, nx2 = 0.f;
            if (t + 1 < TILES_PER_WAVE) {        // constant-folded per t
                nx0 = xp0[off + 16];
                nx1 = xp1[off + 16];
                nx2 = xp2[off + 16];
            }
            // shared x B-frag (quads>=1 zeroed: R8 semantics), packed ONCE
            const int p01 = pkrtz(c0, c1);
            const int p2  = pkrtz(c2, 0.f);
            Frag xf;
            xf.i[0] = isq0 ? p01 : 0;
            xf.i[1] = isq0 ? p2  : 0;

            // layer 1: 4 independent MFMAs
            float4_t acc[FPB];
#pragma unroll
            for (int f = 0; f < FPB; ++f) acc[f] = MFMA16(a1w[f].v, xf.v, b1v[f]);
            Frag hf[FPB];
#pragma unroll
            for (int f = 0; f < FPB; ++f) {
                hf[f].i[0] = pkrtz(fmaxf(acc[f].x, 0.f), fmaxf(acc[f].y, 0.f));
                hf[f].i[1] = pkrtz(fmaxf(acc[f].z, 0.f), fmaxf(acc[f].w, 0.f));
            }
            // layer 2
#pragma unroll
            for (int f = 0; f < FPB; ++f) acc[f] = MFMA16(a2w[f].v, hf[f].v, b2v[f]);
#pragma unroll
            for (int f = 0; f < FPB; ++f) {
                hf[f].i[0] = pkrtz(fmaxf(acc[f].x, 0.f), fmaxf(acc[f].y, 0.f));
                hf[f].i[1] = pkrtz(fmaxf(acc[f].z, 0.f), fmaxf(acc[f].w, 0.f));
            }
            // layer 3 (no relu)
#pragma unroll
            for (int f = 0; f < FPB; ++f) acc[f] = MFMA16(a3w[f].v, hf[f].v, b3v[f]);
            if (isq0) {
#pragma unroll
                for (int f = 0; f < FPB; ++f) {
                    op0[f][off] = acc[f].x;
                    op1[f][off] = acc[f].y;
                    op2[f][off] = acc[f].z;
                }
            }
            c0 = nx0; c1 = nx1; c2 = nx2;
        }
    } else {
        // tail path (never taken for N=1e6): guarded serial tiles
#pragma unroll 1
        for (int t = 0; t < TILES_PER_WAVE; ++t) {
            const int off = t * 16;
            const int pt = base + off + n16;
            float x0 = 0.f, x1v = 0.f, x2v = 0.f;
            if (isq0 && pt < N) {
                x0  = xp0[off];
                x1v = xp1[off];
                x2v = xp2[off];
            }
            Frag xf;
            xf.i[0] = pkrtz(x0, x1v);
            xf.i[1] = pkrtz(x2v, 0.f);
#pragma unroll
            for (int f = 0; f < FPB; ++f) {
                float4_t acc = MFMA16(a1w[f].v, xf.v, b1v[f]);
                Frag bf;
                bf.i[0] = pkrtz(fmaxf(acc.x, 0.f), fmaxf(acc.y, 0.f));
                bf.i[1] = pkrtz(fmaxf(acc.z, 0.f), fmaxf(acc.w, 0.f));
                acc = MFMA16(a2w[f].v, bf.v, b2v[f]);
                Frag cf;
                cf.i[0] = pkrtz(fmaxf(acc.x, 0.f), fmaxf(acc.y, 0.f));
                cf.i[1] = pkrtz(fmaxf(acc.z, 0.f), fmaxf(acc.w, 0.f));
                acc = MFMA16(a3w[f].v, cf.v, b3v[f]);
                if (isq0 && pt < N) {
                    op0[f][off] = acc.x;
                    op1[f][off] = acc.y;
                    op2[f][off] = acc.z;
                }
            }
        }
    }
}

extern "C" void kernel_launch(void* const* d_in, const int* in_sizes, int n_in,
                              void* d_out, int out_size, void* d_ws, size_t ws_size,
                              hipStream_t stream) {
    const float* x  = (const float*)d_in[0];
    const float* W1 = (const float*)d_in[1];
    const float* b1 = (const float*)d_in[2];
    const float* W2 = (const float*)d_in[3];
    const float* b2 = (const float*)d_in[4];
    const float* W3 = (const float*)d_in[5];
    const float* b3 = (const float*)d_in[6];
    float* out = (float*)d_out;

    const int N = in_sizes[0] / 3;  // x is [1,3,N]
    const int chunks = (N + PTS_PER_BLOCK - 1) / PTS_PER_BLOCK;   // 625
    const int a_max  = (chunks + 7) / 8;                          // 79
    const int grid   = 8 * 4 * a_max;                             // 2528
    fields_r10_kernel<<<grid, 256, 0, stream>>>(x, W1, b1, W2, b2, W3, b3, out, N);
}

// Round 6
// 276.126 us; speedup vs baseline: 1.0086x; 1.0086x over previous
//
#include <hip/hip_runtime.h>

// R11: R10 dataflow (4-field group/block, layer-wise ILP, XCD swizzle — which
// fixed FETCH 47.6->6.6MB) with the register-pressure + VALU diet:
//  - All global addressing via wave-UNIFORM bases (no n16 folded in) so the
//    compiler keeps bases in SGPR pairs and uses SADDR+voffset+imm form.
//    One shared offset VGPR instead of ~15 per-lane 64-bit pointers.
//    (R10: VGPR=80, Occupancy 29%, and VALUBusy ~6x the hand-counted VALU
//    work -> likely AGPR accvgpr shuffles from pressure. This is the fix.)
//  - relu in packed f16: cvt_pkrtz then __builtin_elementwise_max with +0
//    (compiler emits v_pk_max_f16; no inline asm). Value-identical to
//    fmaxf(f32)->pkrtz for relu: RTZ(neg) stays neg -> max gives +0;
//    positives unchanged; no NaNs exist here. 6->4 VALU per transition.
//    (Clean A/B on R7's suspect: if this fails like R7, pk-relu is the
//    culprit and gets reverted permanently.)
// Numerics otherwise byte-for-byte R10: a1 quad-broadcast, B-frag quads>=1
// zeroed via cndmask, biases ride the MFMA C operand (fp32), weights RNE,
// activations RTZ.
//
// Frag layouts (16x16x16, CDNA family):
//   A[m][k]: lane m=lane&15, k = 4*(lane>>4) + j   (4 f16, 2 VGPRs)
//   B[k][n]: lane n=lane&15, k = 4*(lane>>4) + j
//   C/D:     lane n=lane&15, row = 4*(lane>>4) + i (4 fp32)

#define MFMA16(a, b, c) __builtin_amdgcn_mfma_f32_16x16x16f16((a), (b), (c), 0, 0, 0)

#define TILES_PER_WAVE 25
#define WAVES_PER_BLOCK 4
#define FPB 4                                            // fields per block
#define PTS_PER_WAVE (TILES_PER_WAVE * 16)               // 400
#define PTS_PER_BLOCK (PTS_PER_WAVE * WAVES_PER_BLOCK)   // 1600; 1e6 = 625*1600

typedef __fp16 pk16x2 __attribute__((ext_vector_type(2)));   // cvt_pkrtz return
typedef _Float16 half4_t __attribute__((ext_vector_type(4)));
typedef float float4_t __attribute__((ext_vector_type(4)));

union H2I { pk16x2 h; int i; };
union Frag { half4_t v; int i[2]; };

__device__ __forceinline__ int pkrtz(float a, float b) {
    H2I u; u.h = __builtin_amdgcn_cvt_pkrtz(a, b); return u.i;
}

// relu on a packed f16 pair: cvt_pkrtz result max'd with +0 (v_pk_max_f16).
__device__ __forceinline__ int pk_relu_pack(float a, float b) {
    H2I u; u.h = __builtin_amdgcn_cvt_pkrtz(a, b);
    const pk16x2 z = {(__fp16)0.f, (__fp16)0.f};
    u.h = __builtin_elementwise_max(u.h, z);
    return u.i;
}

__global__ __launch_bounds__(256) void fields_r11_kernel(
    const float* __restrict__ x,
    const float* __restrict__ W1, const float* __restrict__ b1,
    const float* __restrict__ W2, const float* __restrict__ b2,
    const float* __restrict__ W3, const float* __restrict__ b3,
    float* __restrict__ out, int N)
{
    const int lane = threadIdx.x & 63;
    const int wave = threadIdx.x >> 6;
    const int q    = lane >> 4;        // quad 0..3
    const int n16  = lane & 15;        // point within tile / row m for A

    // ---- XCD-swizzled decode: chunk c = 8a + r runs on XCD r = c%8;
    //      the 4 dgroup-blocks of a chunk sit in one 32-block window. ----
    const int bid = blockIdx.x;
    const int r   = bid & 7;
    const int dg  = (bid >> 3) & 3;    // field group: fields 4*dg .. 4*dg+3
    const int a   = bid >> 5;
    const int chunk  = a * 8 + r;
    const int chunks = (N + PTS_PER_BLOCK - 1) / PTS_PER_BLOCK;
    if (chunk >= chunks) return;       // pad blocks (grid rounded to *8)

    const int base = chunk * PTS_PER_BLOCK + wave * PTS_PER_WAVE;
    const bool isq0 = (q == 0);

    // ---- 4 fields' weights -> registers, frag-ready (constant-indexed) ----
    Frag a1w[FPB], a2w[FPB], a3w[FPB];
    float4_t b1v[FPB], b2v[FPB], b3v[FPB];
#pragma unroll
    for (int f = 0; f < FPB; ++f) {
        const int d = dg * FPB + f;
        const float* w1 = W1 + (d * 16 + n16) * 3;
        a1w[f].v = (half4_t){(_Float16)w1[0], (_Float16)w1[1],
                             (_Float16)w1[2], (_Float16)0.f};
        const float4_t w2 = *(const float4_t*)(W2 + (d * 16 + n16) * 16 + q * 4);
        a2w[f].v = (half4_t){(_Float16)w2.x, (_Float16)w2.y, (_Float16)w2.z,
                             (_Float16)w2.w};
        if (n16 < 3) {
            const float4_t w3 = *(const float4_t*)(W3 + (d * 3 + n16) * 16 + q * 4);
            a3w[f].v = (half4_t){(_Float16)w3.x, (_Float16)w3.y, (_Float16)w3.z,
                                 (_Float16)w3.w};
        } else {
            a3w[f].i[0] = 0; a3w[f].i[1] = 0;
        }
        b1v[f] = *(const float4_t*)(b1 + d * 16 + q * 4);
        b2v[f] = *(const float4_t*)(b2 + d * 16 + q * 4);
        float4_t bb3 = (float4_t){0.f, 0.f, 0.f, 0.f};
        if (isq0) {
            bb3.x = b3[d * 3 + 0];
            bb3.y = b3[d * 3 + 1];
            bb3.z = b3[d * 3 + 2];
        }
        b3v[f] = bb3;
    }

    // ---- UNIFORM base pointers (no n16!) -> SGPR pairs; per-lane part is
    //      the shared [n16 + const] index in each access. ----
    const float* xb0 = x + base;
    const float* xb1 = xb0 + N;
    const float* xb2 = xb1 + N;
    float* ob[FPB][3];
#pragma unroll
    for (int f = 0; f < FPB; ++f) {
        const int d = dg * FPB + f;
#pragma unroll
        for (int i = 0; i < 3; ++i)
            ob[f][i] = out + (size_t)(d * 3 + i) * N + base;
    }

    if (base + PTS_PER_WAVE <= N) {
        // ===== fast path: register-rotate prefetch + layer-wise 4-field ILP
        float c0 = xb0[n16], c1 = xb1[n16], c2 = xb2[n16];
#pragma unroll
        for (int t = 0; t < TILES_PER_WAVE; ++t) {
            const int off = t * 16;
            float nx0 = 0.f, nx1 = 0.f, nx2 = 0.f;
            if (t + 1 < TILES_PER_WAVE) {        // constant-folded per t
                nx0 = xb0[n16 + off + 16];
                nx1 = xb1[n16 + off + 16];
                nx2 = xb2[n16 + off + 16];
            }
            // shared x B-frag (quads>=1 zeroed: known-good semantics)
            const int p01 = pkrtz(c0, c1);
            const int p2  = pkrtz(c2, 0.f);
            Frag xf;
            xf.i[0] = isq0 ? p01 : 0;
            xf.i[1] = isq0 ? p2  : 0;

            // layer 1: 4 independent MFMAs
            float4_t acc[FPB];
#pragma unroll
            for (int f = 0; f < FPB; ++f) acc[f] = MFMA16(a1w[f].v, xf.v, b1v[f]);
            Frag hf[FPB];
#pragma unroll
            for (int f = 0; f < FPB; ++f) {
                hf[f].i[0] = pk_relu_pack(acc[f].x, acc[f].y);
                hf[f].i[1] = pk_relu_pack(acc[f].z, acc[f].w);
            }
            // layer 2
#pragma unroll
            for (int f = 0; f < FPB; ++f) acc[f] = MFMA16(a2w[f].v, hf[f].v, b2v[f]);
#pragma unroll
            for (int f = 0; f < FPB; ++f) {
                hf[f].i[0] = pk_relu_pack(acc[f].x, acc[f].y);
                hf[f].i[1] = pk_relu_pack(acc[f].z, acc[f].w);
            }
            // layer 3 (no relu)
#pragma unroll
            for (int f = 0; f < FPB; ++f) acc[f] = MFMA16(a3w[f].v, hf[f].v, b3v[f]);
            if (isq0) {
#pragma unroll
                for (int f = 0; f < FPB; ++f) {
                    ob[f][0][n16 + off] = acc[f].x;
                    ob[f][1][n16 + off] = acc[f].y;
                    ob[f][2][n16 + off] = acc[f].z;
                }
            }
            c0 = nx0; c1 = nx1; c2 = nx2;
        }
    } else {
        // tail path (never taken for N=1e6): guarded serial tiles
#pragma unroll 1
        for (int t = 0; t < TILES_PER_WAVE; ++t) {
            const int off = t * 16;
            const int pt = base + off + n16;
            float x0 = 0.f, x1v = 0.f, x2v = 0.f;
            if (isq0 && pt < N) {
                x0  = xb0[n16 + off];
                x1v = xb1[n16 + off];
                x2v = xb2[n16 + off];
            }
            Frag xf;
            xf.i[0] = pkrtz(x0, x1v);
            xf.i[1] = pkrtz(x2v, 0.f);
#pragma unroll
            for (int f = 0; f < FPB; ++f) {
                float4_t acc = MFMA16(a1w[f].v, xf.v, b1v[f]);
                Frag bf;
                bf.i[0] = pk_relu_pack(acc.x, acc.y);
                bf.i[1] = pk_relu_pack(acc.z, acc.w);
                acc = MFMA16(a2w[f].v, bf.v, b2v[f]);
                Frag cf;
                cf.i[0] = pk_relu_pack(acc.x, acc.y);
                cf.i[1] = pk_relu_pack(acc.z, acc.w);
                acc = MFMA16(a3w[f].v, cf.v, b3v[f]);
                if (isq0 && pt < N) {
                    ob[f][0][n16 + off] = acc.x;
                    ob[f][1][n16 + off] = acc.y;
                    ob[f][2][n16 + off] = acc.z;
                }
            }
        }
    }
}

extern "C" void kernel_launch(void* const* d_in, const int* in_sizes, int n_in,
                              void* d_out, int out_size, void* d_ws, size_t ws_size,
                              hipStream_t stream) {
    const float* x  = (const float*)d_in[0];
    const float* W1 = (const float*)d_in[1];
    const float* b1 = (const float*)d_in[2];
    const float* W2 = (const float*)d_in[3];
    const float* b2 = (const float*)d_in[4];
    const float* W3 = (const float*)d_in[5];
    const float* b3 = (const float*)d_in[6];
    float* out = (float*)d_out;

    const int N = in_sizes[0] / 3;  // x is [1,3,N]
    const int chunks = (N + PTS_PER_BLOCK - 1) / PTS_PER_BLOCK;   // 625
    const int a_max  = (chunks + 7) / 8;                          // 79
    const int grid   = 8 * 4 * a_max;                             // 2528
    fields_r11_kernel<<<grid, 256, 0, stream>>>(x, W1, b1, W2, b2, W3, b3, out, N);
}

// Round 7
// 250.669 us; speedup vs baseline: 1.1111x; 1.1016x over previous
//
#include <hip/hip_runtime.h>

// R12: R9's proven 5-deep double-buffered pipeline x R10's x-reuse, with the
// register budget engineered for 4 waves/SIMD.
// Evidence trail: R9 (FPB=1, GP=5 prefetch) ~97us; R10/R11 (FPB=4) ~116us at
// Occupancy 28% == 2 waves/SIMD despite VGPR_Count=80 -> legacy-MFMA accs
// went to AGPRs (unified file: 80+acc>128 total), plus accvgpr shuffles
// inflating VALU. R12:
//  - FPB=2 fields/block, GP=5 tile groups, xb[2][3][5] double-buffer
//    (15 loads in flight, 5 tiles ahead) — R9's exact prefetch pattern.
//  - per group: pack x ONCE, then per field sequentially
//    {5x L1 MFMA, relu, 5x L2, relu, 5x L3, store}: acc[5]/hf[5] reused
//    across fields -> live state ~105 regs.
//  - __launch_bounds__(256, 4): min 4 waves/EU -> allocator must fit <=128
//    regs total (VGPR+AGPR) -> guards against the AGPR occupancy collapse.
//  - XCD swizzle: bid = r + 8*fg + 64*a, chunk = 8a+r -> a chunk's 8
//    field-group blocks run on XCD chunk%8 within a 64-block window.
// Numerics bit-identical to R11 (passed, absmax 0.001953125): a1
// quad-broadcast, B-frag quads>=1 zeroed via cndmask, pk_relu_pack
// (cvt_pkrtz + v_pk_max_f16), biases ride the MFMA C operand (fp32).
//
// Frag layouts (16x16x16, CDNA family):
//   A[m][k]: lane m=lane&15, k = 4*(lane>>4) + j   (4 f16, 2 VGPRs)
//   B[k][n]: lane n=lane&15, k = 4*(lane>>4) + j
//   C/D:     lane n=lane&15, row = 4*(lane>>4) + i (4 fp32)

#define MFMA16(a, b, c) __builtin_amdgcn_mfma_f32_16x16x16f16((a), (b), (c), 0, 0, 0)

#define GP 5                       // tiles per group
#define NG 5                       // groups per wave
#define TILES_PER_WAVE (GP * NG)   // 25
#define WAVES_PER_BLOCK 4
#define FPB 2                      // fields per block
#define PTS_PER_WAVE (TILES_PER_WAVE * 16)               // 400
#define PTS_PER_BLOCK (PTS_PER_WAVE * WAVES_PER_BLOCK)   // 1600; 1e6=625*1600

typedef __fp16 pk16x2 __attribute__((ext_vector_type(2)));   // cvt_pkrtz return
typedef _Float16 half4_t __attribute__((ext_vector_type(4)));
typedef float float4_t __attribute__((ext_vector_type(4)));

union H2I { pk16x2 h; int i; };
union Frag { half4_t v; int i[2]; };

__device__ __forceinline__ int pkrtz(float a, float b) {
    H2I u; u.h = __builtin_amdgcn_cvt_pkrtz(a, b); return u.i;
}

// relu on a packed f16 pair: cvt_pkrtz then v_pk_max_f16 with +0 (R11-proven)
__device__ __forceinline__ int pk_relu_pack(float a, float b) {
    H2I u; u.h = __builtin_amdgcn_cvt_pkrtz(a, b);
    const pk16x2 z = {(__fp16)0.f, (__fp16)0.f};
    u.h = __builtin_elementwise_max(u.h, z);
    return u.i;
}

__global__ __launch_bounds__(256, 4) void fields_r12_kernel(
    const float* __restrict__ x,
    const float* __restrict__ W1, const float* __restrict__ b1,
    const float* __restrict__ W2, const float* __restrict__ b2,
    const float* __restrict__ W3, const float* __restrict__ b3,
    float* __restrict__ out, int N)
{
    const int lane = threadIdx.x & 63;
    const int wave = threadIdx.x >> 6;
    const int q    = lane >> 4;        // quad 0..3
    const int n16  = lane & 15;        // point within tile / row m for A

    // ---- XCD-swizzled decode: chunk c = 8a + r runs on XCD r = c%8;
    //      a chunk's 8 field-group blocks sit in one 64-block window. ----
    const int bid = blockIdx.x;
    const int r   = bid & 7;
    const int fg  = (bid >> 3) & 7;    // field group: fields 2*fg, 2*fg+1
    const int a   = bid >> 6;
    const int chunk  = a * 8 + r;
    const int chunks = (N + PTS_PER_BLOCK - 1) / PTS_PER_BLOCK;
    if (chunk >= chunks) return;       // pad blocks (grid rounded to *8)

    const int base = chunk * PTS_PER_BLOCK + wave * PTS_PER_WAVE;
    const bool isq0 = (q == 0);

    // ---- 2 fields' weights -> registers, frag-ready (constant-indexed) ----
    Frag a1w[FPB], a2w[FPB], a3w[FPB];
    float4_t b1v[FPB], b2v[FPB], b3v[FPB];
#pragma unroll
    for (int f = 0; f < FPB; ++f) {
        const int d = fg * FPB + f;
        const float* w1 = W1 + (d * 16 + n16) * 3;
        a1w[f].v = (half4_t){(_Float16)w1[0], (_Float16)w1[1],
                             (_Float16)w1[2], (_Float16)0.f};
        const float4_t w2 = *(const float4_t*)(W2 + (d * 16 + n16) * 16 + q * 4);
        a2w[f].v = (half4_t){(_Float16)w2.x, (_Float16)w2.y, (_Float16)w2.z,
                             (_Float16)w2.w};
        if (n16 < 3) {
            const float4_t w3 = *(const float4_t*)(W3 + (d * 3 + n16) * 16 + q * 4);
            a3w[f].v = (half4_t){(_Float16)w3.x, (_Float16)w3.y, (_Float16)w3.z,
                                 (_Float16)w3.w};
        } else {
            a3w[f].i[0] = 0; a3w[f].i[1] = 0;
        }
        b1v[f] = *(const float4_t*)(b1 + d * 16 + q * 4);
        b2v[f] = *(const float4_t*)(b2 + d * 16 + q * 4);
        float4_t bb3 = (float4_t){0.f, 0.f, 0.f, 0.f};
        if (isq0) {
            bb3.x = b3[d * 3 + 0];
            bb3.y = b3[d * 3 + 1];
            bb3.z = b3[d * 3 + 2];
        }
        b3v[f] = bb3;
    }

    // ---- UNIFORM base pointers (no n16) -> SGPR pairs; per-lane index is
    //      [n16 + const] in each access (SADDR + voffset + imm form). ----
    const float* xb0 = x + base;
    const float* xb1 = xb0 + N;
    const float* xb2 = xb1 + N;
    float* ob[FPB][3];
#pragma unroll
    for (int f = 0; f < FPB; ++f) {
        const int d = fg * FPB + f;
#pragma unroll
        for (int i = 0; i < 3; ++i)
            ob[f][i] = out + (size_t)(d * 3 + i) * N + base;
    }

    if (base + PTS_PER_WAVE <= N) {
        // ===== fast path: 5-deep double-buffered prefetch, layer-wise =====
        float xb[2][3][GP];   // [buf][row][tile] — all indices compile-time
#pragma unroll
        for (int t = 0; t < GP; ++t) {         // prologue: load group 0
            xb[0][0][t] = xb0[n16 + t * 16];
            xb[0][1][t] = xb1[n16 + t * 16];
            xb[0][2][t] = xb2[n16 + t * 16];
        }
#pragma unroll
        for (int g = 0; g < NG; ++g) {
            const int b = g & 1;               // compile-time after unroll
            if (g + 1 < NG) {                  // prefetch group g+1
                const int nb = (g + 1) & 1;
#pragma unroll
                for (int t = 0; t < GP; ++t) {
                    const int off = n16 + ((g + 1) * GP + t) * 16;
                    xb[nb][0][t] = xb0[off];
                    xb[nb][1][t] = xb1[off];
                    xb[nb][2][t] = xb2[off];
                }
            }
            // pack x -> B-frags ONCE per group (shared by both fields)
            Frag xf[GP];
#pragma unroll
            for (int t = 0; t < GP; ++t) {
                const int p01 = pkrtz(xb[b][0][t], xb[b][1][t]);
                const int p2  = pkrtz(xb[b][2][t], 0.f);
                xf[t].i[0] = isq0 ? p01 : 0;
                xf[t].i[1] = isq0 ? p2  : 0;
            }
            // fields sequentially; acc/hf reused -> bounded live state
#pragma unroll
            for (int f = 0; f < FPB; ++f) {
                float4_t acc[GP];
#pragma unroll
                for (int t = 0; t < GP; ++t)
                    acc[t] = MFMA16(a1w[f].v, xf[t].v, b1v[f]);
                Frag hf[GP];
#pragma unroll
                for (int t = 0; t < GP; ++t) {
                    hf[t].i[0] = pk_relu_pack(acc[t].x, acc[t].y);
                    hf[t].i[1] = pk_relu_pack(acc[t].z, acc[t].w);
                }
#pragma unroll
                for (int t = 0; t < GP; ++t)
                    acc[t] = MFMA16(a2w[f].v, hf[t].v, b2v[f]);
#pragma unroll
                for (int t = 0; t < GP; ++t) {
                    hf[t].i[0] = pk_relu_pack(acc[t].x, acc[t].y);
                    hf[t].i[1] = pk_relu_pack(acc[t].z, acc[t].w);
                }
#pragma unroll
                for (int t = 0; t < GP; ++t)
                    acc[t] = MFMA16(a3w[f].v, hf[t].v, b3v[f]);
                if (isq0) {
#pragma unroll
                    for (int t = 0; t < GP; ++t) {
                        const int off = n16 + (g * GP + t) * 16;
                        ob[f][0][off] = acc[t].x;
                        ob[f][1][off] = acc[t].y;
                        ob[f][2][off] = acc[t].z;
                    }
                }
            }
        }
    } else {
        // tail path (never taken for N=1e6): guarded serial tiles
#pragma unroll 1
        for (int t = 0; t < TILES_PER_WAVE; ++t) {
            const int off = t * 16;
            const int pt = base + off + n16;
            float x0 = 0.f, x1v = 0.f, x2v = 0.f;
            if (isq0 && pt < N) {
                x0  = xb0[n16 + off];
                x1v = xb1[n16 + off];
                x2v = xb2[n16 + off];
            }
            Frag xf;
            xf.i[0] = pkrtz(x0, x1v);
            xf.i[1] = pkrtz(x2v, 0.f);
#pragma unroll
            for (int f = 0; f < FPB; ++f) {
                float4_t acc = MFMA16(a1w[f].v, xf.v, b1v[f]);
                Frag bf;
                bf.i[0] = pk_relu_pack(acc.x, acc.y);
                bf.i[1] = pk_relu_pack(acc.z, acc.w);
                acc = MFMA16(a2w[f].v, bf.v, b2v[f]);
                Frag cf;
                cf.i[0] = pk_relu_pack(acc.x, acc.y);
                cf.i[1] = pk_relu_pack(acc.z, acc.w);
                acc = MFMA16(a3w[f].v, cf.v, b3v[f]);
                if (isq0 && pt < N) {
                    ob[f][0][n16 + off] = acc.x;
                    ob[f][1][n16 + off] = acc.y;
                    ob[f][2][n16 + off] = acc.z;
                }
            }
        }
    }
}

extern "C" void kernel_launch(void* const* d_in, const int* in_sizes, int n_in,
                              void* d_out, int out_size, void* d_ws, size_t ws_size,
                              hipStream_t stream) {
    const float* x  = (const float*)d_in[0];
    const float* W1 = (const float*)d_in[1];
    const float* b1 = (const float*)d_in[2];
    const float* W2 = (const float*)d_in[3];
    const float* b2 = (const float*)d_in[4];
    const float* W3 = (const float*)d_in[5];
    const float* b3 = (const float*)d_in[6];
    float* out = (float*)d_out;

    const int N = in_sizes[0] / 3;  // x is [1,3,N]
    const int chunks = (N + PTS_PER_BLOCK - 1) / PTS_PER_BLOCK;   // 625
    const int a_max  = (chunks + 7) / 8;                          // 79
    const int grid   = 8 * 8 * a_max;                             // 5056
    fields_r12_kernel<<<grid, 256, 0, stream>>>(x, W1, b1, W2, b2, W3, b3, out, N);
}